// Round 11
// baseline (178.905 us; speedup 1.0000x reference)
//
#include <hip/hip_runtime.h>

// Window attention, register-resident MFMA version (R11).
// One WG (512 thr = 8 waves) per 7x7 window; wave = head.
// R11 vs R10 (all latency-chain cuts, structure unchanged):
//  (1) softmax bias gathers batched: kcc[16] precomputed, 16 ds_reads issued
//      into bb[] before the exp2 chain (was 64 interleaved read->exp deps);
//      masked lanes get bb=-10000 -> exp2 yields 0, no divergent select on e.
//  (2) P packed UNNORMALIZED; 1/sum multiplied into oacc after pass 4
//      (32 muls vs 64, and the shfl-reduce+rcp moves off the critical path,
//      overlapping the pre-O-write barrier).
//  (3) P-pack uses v_cvt_pkrtz (1 VALU); Q/K/V/O packs stay RNE for accuracy.
// LDS = max(X/O tile 32KB, out_s 50.96KB) + bias 5.63KB = 56592 B.

typedef _Float16 half_t;
typedef _Float16 half8 __attribute__((ext_vector_type(8)));
typedef _Float16 half4 __attribute__((ext_vector_type(4)));
typedef float    f32x4 __attribute__((ext_vector_type(4)));

#define MFMA16(a, b, c) __builtin_amdgcn_mfma_f32_16x16x32_f16((a), (b), (c), 0, 0, 0)

__global__ __launch_bounds__(256) void convert_w(const float* __restrict__ qkv_w,
                                                 const float* __restrict__ proj_w,
                                                 half_t* __restrict__ w16) {
    int i = blockIdx.x * 256 + threadIdx.x;           // grid covers exactly 262144
    if (i < 768 * 256) w16[i] = (half_t)qkv_w[i];
    else               w16[i] = (half_t)proj_w[i - 768 * 256];
}

// pack two f32 -> one dword of 2 fp16 (RNE; used for Q/K/V)
static __device__ __forceinline__ unsigned pk2(float a, float b) {
    union { half_t h[2]; unsigned u; } t;
    t.h[0] = (half_t)a; t.h[1] = (half_t)b; return t.u;
}
// pack two f32 -> one dword of 2 fp16 (RTZ, single instr; used for P)
static __device__ __forceinline__ unsigned pk2z(float a, float b) {
    return __builtin_bit_cast(unsigned, __builtin_amdgcn_cvt_pkrtz(a, b));
}

// Build an A/B-frag (8 fp16): element C[8g+j][l15] of the C-layout tile pair
// (p0 = rows 0..15, p1 = rows 16..31), pairs packed along rows (K-dim).
static __device__ __forceinline__ half8 frag_pk(unsigned p0l, unsigned p0h,
                                                unsigned p1l, unsigned p1h,
                                                int srcA, int srcB, bool lo) {
    unsigned a0 = __shfl(p0l, srcA, 64), a1 = __shfl(p0h, srcA, 64);
    unsigned a2 = __shfl(p0l, srcB, 64), a3 = __shfl(p0h, srcB, 64);
    unsigned b0 = __shfl(p1l, srcA, 64), b1 = __shfl(p1h, srcA, 64);
    unsigned b2 = __shfl(p1l, srcB, 64), b3 = __shfl(p1h, srcB, 64);
    uint4 fr;
    fr.x = lo ? a0 : b0; fr.y = lo ? a1 : b1;
    fr.z = lo ? a2 : b2; fr.w = lo ? a3 : b3;
    return __builtin_bit_cast(half8, fr);
}

__global__ __launch_bounds__(512, 4) void winattn_mfma(
    const float* __restrict__ x,
    const float* __restrict__ qkv_b,
    const float* __restrict__ proj_b,
    const float* __restrict__ bias_table,
    const half_t* __restrict__ w16,
    float* __restrict__ out)
{
    constexpr int C = 256;
    __shared__ __align__(16) char smem[56592];
    float* out_s  = (float*)smem;                     // [49][260] fp32 (late)
    float* bias_s = (float*)(smem + 50960);           // [8][176] fp32 * log2e

    const int tid  = threadIdx.x;
    const int wave = tid >> 6;
    const int lane = tid & 63;
    const int g    = lane >> 4;
    const int l15  = lane & 15;

    const int wid = blockIdx.x;
    const int b   = wid >> 6;
    const int wy  = (wid >> 3) & 7;
    const int wx  = wid & 7;
    const float* xbase = x   + (size_t)b * 3136 * C;
    float*       obase = out + (size_t)b * 3136 * C;

    const float LOG2E = 1.4426950408889634f;

    // bias_table is [169][8]; store transposed as [h][idx], pre-scaled by log2e
    for (int i = tid; i < 169 * 8; i += 512)
        bias_s[(i & 7) * 176 + (i >> 3)] = bias_table[i] * LOG2E;

    // ---- stage X fp32->fp16 [64][256], rows 49..63 zero, swizzle byte^=(row&15)<<4
    for (int i = tid; i < 64 * 32; i += 512) {
        int row = i >> 5, ch = i & 31;
        char* dst = smem + row * 512 + ((ch * 16) ^ ((row & 15) << 4));
        if (row < 49) {
            int ti = row / 7, tj = row % 7;
            const float* src = xbase + ((wy * 7 + ti) * 56 + (wx * 7 + tj)) * C + ch * 8;
            float4 f0 = ((const float4*)src)[0];
            float4 f1 = ((const float4*)src)[1];
            half8 v = { (half_t)f0.x, (half_t)f0.y, (half_t)f0.z, (half_t)f0.w,
                        (half_t)f1.x, (half_t)f1.y, (half_t)f1.z, (half_t)f1.w };
            *(half8*)dst = v;
        } else {
            half8 v = { (half_t)0, (half_t)0, (half_t)0, (half_t)0,
                        (half_t)0, (half_t)0, (half_t)0, (half_t)0 };
            *(half8*)dst = v;
        }
    }
    __syncthreads();

    const int h = wave;
    const int srcA = (g & 1) * 32 + l15;
    const int srcB = srcA + 16;
    const bool lo = (g < 2);
    const f32x4 fz = {0.f, 0.f, 0.f, 0.f};
    // scale * log2e folded together: S*log2e comes out of the MFMA via Q
    const float SCALE2 = 0.17677669529663687f * 1.4426950408889634f;

    // ================= pass 1: Q^T,K^T = W*X^T  (M=d 2 tiles, N=t 4 tiles)
    f32x4 qacc[2][4], kacc[2][4];
    #pragma unroll
    for (int mt = 0; mt < 2; ++mt)
        #pragma unroll
        for (int nt = 0; nt < 4; ++nt) { qacc[mt][nt] = fz; kacc[mt][nt] = fz; }

    #pragma unroll
    for (int s = 0; s < 8; ++s) {
        half8 xf[4];
        #pragma unroll
        for (int nt = 0; nt < 4; ++nt) {
            int row = nt * 16 + l15;
            xf[nt] = *(const half8*)(smem + row * 512 + ((s * 64 + g * 16) ^ ((row & 15) << 4)));
        }
        half8 wqf[2], wkf[2];
        #pragma unroll
        for (int mt = 0; mt < 2; ++mt) {
            int d = h * 32 + mt * 16 + l15;
            wqf[mt] = *(const half8*)(w16 + (size_t)d * 256 + s * 32 + g * 8);
            wkf[mt] = *(const half8*)(w16 + (size_t)(256 + d) * 256 + s * 32 + g * 8);
        }
        #pragma unroll
        for (int mt = 0; mt < 2; ++mt)
            #pragma unroll
            for (int nt = 0; nt < 4; ++nt) {
                qacc[mt][nt] = MFMA16(wqf[mt], xf[nt], qacc[mt][nt]);
                kacc[mt][nt] = MFMA16(wkf[mt], xf[nt], kacc[mt][nt]);
            }
    }

    // pack Q^T (bias, *scale*log2e) / K^T (bias) to fp16 dwords
    unsigned pkq[2][4][2], pkk[2][4][2];
    #pragma unroll
    for (int mt = 0; mt < 2; ++mt) {
        float bq[4], bk[4];
        #pragma unroll
        for (int r = 0; r < 4; ++r) {
            int d = h * 32 + mt * 16 + 4 * g + r;
            bq[r] = qkv_b[d];
            bk[r] = qkv_b[256 + d];
        }
        #pragma unroll
        for (int nt = 0; nt < 4; ++nt) {
            pkq[mt][nt][0] = pk2((qacc[mt][nt][0] + bq[0]) * SCALE2,
                                 (qacc[mt][nt][1] + bq[1]) * SCALE2);
            pkq[mt][nt][1] = pk2((qacc[mt][nt][2] + bq[2]) * SCALE2,
                                 (qacc[mt][nt][3] + bq[3]) * SCALE2);
            pkk[mt][nt][0] = pk2(kacc[mt][nt][0] + bk[0], kacc[mt][nt][1] + bk[1]);
            pkk[mt][nt][1] = pk2(kacc[mt][nt][2] + bk[2], kacc[mt][nt][3] + bk[3]);
        }
    }

    // ================= pass 2: S^T(*log2e) = K * Q^T  (M=k, N=q, K=32)
    half8 bqf[4];
    #pragma unroll
    for (int nt = 0; nt < 4; ++nt)
        bqf[nt] = frag_pk(pkq[0][nt][0], pkq[0][nt][1],
                          pkq[1][nt][0], pkq[1][nt][1], srcA, srcB, lo);
    f32x4 st[4][4];
    #pragma unroll
    for (int mt = 0; mt < 4; ++mt)
        #pragma unroll
        for (int nt = 0; nt < 4; ++nt) st[mt][nt] = fz;
    #pragma unroll
    for (int mt = 0; mt < 4; ++mt) {
        half8 ak = frag_pk(pkk[0][mt][0], pkk[0][mt][1],
                           pkk[1][mt][0], pkk[1][mt][1], srcA, srcB, lo);
        #pragma unroll
        for (int nt = 0; nt < 4; ++nt)
            st[mt][nt] = MFMA16(ak, bqf[nt], st[mt][nt]);
    }

    // ---- max-free softmax over k (base-2). Bias loads batched per q-tile;
    // masked k (>=49) get bb=-10000 -> exp2 -> 0 (no divergent select on e).
    int qcode[4];
    #pragma unroll
    for (int nt = 0; nt < 4; ++nt) {
        int q = nt * 16 + l15; if (q > 48) q = 48;
        qcode[nt] = (q / 7) * 13 + (q % 7) + 84;
    }
    int  kcc[16];
    bool kvv[16];
    #pragma unroll
    for (int mt = 0; mt < 4; ++mt)
        #pragma unroll
        for (int r = 0; r < 4; ++r) {
            int k = mt * 16 + 4 * g + r;
            kvv[mt * 4 + r] = (k < 49);
            kcc[mt * 4 + r] = (k < 49) ? ((k / 7) * 13 + (k % 7)) : 0;
        }
    const float* bias_h = bias_s + h * 176;
    float sm0[4] = {0.f, 0.f, 0.f, 0.f};     // partials r=0,1
    float sm1[4] = {0.f, 0.f, 0.f, 0.f};     // partials r=2,3
    #pragma unroll
    for (int nt = 0; nt < 4; ++nt) {
        float bb[16];
        #pragma unroll
        for (int i = 0; i < 16; ++i)
            bb[i] = kvv[i] ? bias_h[qcode[nt] - kcc[i]] : -10000.f;
        #pragma unroll
        for (int mt = 0; mt < 4; ++mt)
            #pragma unroll
            for (int r = 0; r < 4; ++r) {
                float e = __builtin_amdgcn_exp2f(st[mt][nt][r] + bb[mt * 4 + r]);
                st[mt][nt][r] = e;
                if (r < 2) sm0[nt] += e; else sm1[nt] += e;
            }
    }
    // pack UNNORMALIZED P (RTZ); 1/sum folded into oacc after pass 4.
    unsigned pkp[4][4][2];
    #pragma unroll
    for (int mt = 0; mt < 4; ++mt)
        #pragma unroll
        for (int nt = 0; nt < 4; ++nt) {
            pkp[mt][nt][0] = pk2z(st[mt][nt][0], st[mt][nt][1]);
            pkp[mt][nt][1] = pk2z(st[mt][nt][2], st[mt][nt][3]);
        }

    // ================= pass 3: V = X * Wv^T  (M=t 4 tiles, N=d 2 tiles)
    // (st dies into pkp above -> registers free for vacc; do NOT reorder
    // V GEMM above the softmax: R8 did and spilled to scratch.)
    f32x4 vacc[4][2];
    #pragma unroll
    for (int mt = 0; mt < 4; ++mt)
        #pragma unroll
        for (int nd = 0; nd < 2; ++nd) vacc[mt][nd] = fz;
    #pragma unroll
    for (int s = 0; s < 8; ++s) {
        half8 xf[4];
        #pragma unroll
        for (int mt = 0; mt < 4; ++mt) {
            int row = mt * 16 + l15;
            xf[mt] = *(const half8*)(smem + row * 512 + ((s * 64 + g * 16) ^ ((row & 15) << 4)));
        }
        half8 wvf[2];
        #pragma unroll
        for (int nd = 0; nd < 2; ++nd) {
            int d = 512 + h * 32 + nd * 16 + l15;
            wvf[nd] = *(const half8*)(w16 + (size_t)d * 256 + s * 32 + g * 8);
        }
        #pragma unroll
        for (int mt = 0; mt < 4; ++mt)
            #pragma unroll
            for (int nd = 0; nd < 2; ++nd)
                vacc[mt][nd] = MFMA16(xf[mt], wvf[nd], vacc[mt][nd]);
    }
    unsigned pkv[4][2][2];
    #pragma unroll
    for (int nd = 0; nd < 2; ++nd) {
        float bv = qkv_b[512 + h * 32 + nd * 16 + l15];
        #pragma unroll
        for (int mt = 0; mt < 4; ++mt) {
            pkv[mt][nd][0] = pk2(vacc[mt][nd][0] + bv, vacc[mt][nd][1] + bv);
            pkv[mt][nd][1] = pk2(vacc[mt][nd][2] + bv, vacc[mt][nd][3] + bv);
        }
    }

    // ================= pass 4: O^T = V^T * P^T  (M=d 2 tiles, N=q 4 tiles, K=64)
    f32x4 oacc[2][4];
    #pragma unroll
    for (int md = 0; md < 2; ++md)
        #pragma unroll
        for (int nq = 0; nq < 4; ++nq) oacc[md][nq] = fz;
    #pragma unroll
    for (int ks = 0; ks < 2; ++ks) {
        half8 avf[2];
        #pragma unroll
        for (int md = 0; md < 2; ++md)
            avf[md] = frag_pk(pkv[2 * ks][md][0], pkv[2 * ks][md][1],
                              pkv[2 * ks + 1][md][0], pkv[2 * ks + 1][md][1],
                              srcA, srcB, lo);
        #pragma unroll
        for (int nq = 0; nq < 4; ++nq) {
            half8 bpf = frag_pk(pkp[2 * ks][nq][0], pkp[2 * ks][nq][1],
                                pkp[2 * ks + 1][nq][0], pkp[2 * ks + 1][nq][1],
                                srcA, srcB, lo);
            #pragma unroll
            for (int md = 0; md < 2; ++md)
                oacc[md][nq] = MFMA16(avf[md], bpf, oacc[md][nq]);
        }
    }

    // softmax denominator reduce, off the MFMA critical path (overlaps barrier)
    float inv[4];
    #pragma unroll
    for (int nt = 0; nt < 4; ++nt) {
        float s2 = sm0[nt] + sm1[nt];
        float ssum = s2 + __shfl_xor(s2, 16, 64);
        ssum += __shfl_xor(ssum, 32, 64);
        inv[nt] = 1.0f / ssum;
    }

    // all waves must be done reading X before O overwrites the tile
    __syncthreads();

    // ---- O write (fp16, normalized here) into X-aliased swizzled tile:
    // 8x ds_write_b64, conflict-free under the 4-bit swizzle
    #pragma unroll
    for (int md = 0; md < 2; ++md)
        #pragma unroll
        for (int nq = 0; nq < 4; ++nq) {
            int q = nq * 16 + l15;
            int dbase = h * 32 + md * 16 + 4 * g;          // 4 consecutive d
            float iv = inv[nq];
            half4 ov = { (half_t)(oacc[md][nq][0] * iv), (half_t)(oacc[md][nq][1] * iv),
                         (half_t)(oacc[md][nq][2] * iv), (half_t)(oacc[md][nq][3] * iv) };
            *(half4*)(smem + q * 512 + ((dbase * 2) ^ ((q & 15) << 4))) = ov;
        }
    __syncthreads();

    // ================= proj (operand-swapped): C = Wp * O^T
    // A = proj-weight rows (feats), B = O^T frags (tokens as cols) ->
    // C rows = feats: each thread holds 4 consecutive feats per token.
    const half_t* pw = w16 + 768 * 256;
    f32x4 pa[2][4];                                   // [feat tile][tok tile]
    #pragma unroll
    for (int mtf = 0; mtf < 2; ++mtf)
        #pragma unroll
        for (int nq = 0; nq < 4; ++nq) pa[mtf][nq] = fz;
    #pragma unroll
    for (int s = 0; s < 8; ++s) {
        half8 of[4], wf[2];
        #pragma unroll
        for (int nq = 0; nq < 4; ++nq) {
            int row = nq * 16 + l15;
            of[nq] = *(const half8*)(smem + row * 512 + ((s * 64 + g * 16) ^ ((row & 15) << 4)));
        }
        #pragma unroll
        for (int mtf = 0; mtf < 2; ++mtf) {
            int f = wave * 32 + mtf * 16 + l15;
            wf[mtf] = *(const half8*)(pw + (size_t)f * 256 + s * 32 + g * 8);
        }
        #pragma unroll
        for (int mtf = 0; mtf < 2; ++mtf)
            #pragma unroll
            for (int nq = 0; nq < 4; ++nq)
                pa[mtf][nq] = MFMA16(wf[mtf], of[nq], pa[mtf][nq]);
    }

    // proj reads of the O tile are done; out_s (fp32) may now overwrite it
    __syncthreads();

    // ---- stage proj output (+bias) into out_s [49][260] fp32: b128 writes
    #pragma unroll
    for (int mtf = 0; mtf < 2; ++mtf) {
        int fbase = wave * 32 + mtf * 16 + 4 * g;      // 4 consecutive feats
        float4 pbv = *(const float4*)&proj_b[fbase];
        #pragma unroll
        for (int nq = 0; nq < 4; ++nq) {
            int tok = nq * 16 + l15;
            if (tok < 49) {
                float4 v = { pa[mtf][nq][0] + pbv.x, pa[mtf][nq][1] + pbv.y,
                             pa[mtf][nq][2] + pbv.z, pa[mtf][nq][3] + pbv.w };
                *(float4*)&out_s[tok * 260 + fbase] = v;
            }
        }
    }
    __syncthreads();

    // ---- write out: one full 1KB token row per wave iteration (fully
    // coalesced, every 128B line visited exactly once)
    for (int i = tid; i < 49 * 64; i += 512) {
        int t = i >> 6, c4 = i & 63;
        float4 v = *(const float4*)&out_s[t * 260 + c4 * 4];
        int ti = t / 7, tj = t % 7;
        *(float4*)&obase[((wy * 7 + ti) * 56 + (wx * 7 + tj)) * C + c4 * 4] = v;
    }
}

extern "C" void kernel_launch(void* const* d_in, const int* in_sizes, int n_in,
                              void* d_out, int out_size, void* d_ws, size_t ws_size,
                              hipStream_t stream) {
    const float* x          = (const float*)d_in[0];
    const float* qkv_w      = (const float*)d_in[3];
    const float* qkv_b      = (const float*)d_in[4];
    const float* proj_w     = (const float*)d_in[5];
    const float* proj_b     = (const float*)d_in[6];
    const float* bias_table = (const float*)d_in[7];
    float* out = (float*)d_out;
    half_t* w16 = (half_t*)d_ws;   // 1024*256 halfs = 524288 B

    hipLaunchKernelGGL(convert_w, dim3(1024), dim3(256), 0, stream,
                       qkv_w, proj_w, w16);
    hipLaunchKernelGGL(winattn_mfma, dim3(2048), dim3(512), 0, stream,
                       x, qkv_b, proj_b, bias_table, w16, out);
}

// Round 12
// 160.562 us; speedup vs baseline: 1.1142x; 1.1142x over previous
//
#include <hip/hip_runtime.h>

// Window attention, register-resident MFMA version (R12).
// One WG (512 thr = 8 waves) per 7x7 window; wave = head.
// R12 = R10 base (R11's bb[16]-batching reverted: it spilled, FETCH 58->105MB)
// plus two register-neutral deltas:
//  (1) O tile in its OWN LDS region (no X alias) -> the pre-O-write barrier
//      is gone (waves store O right after pass 4). X 32K | O 32K | bias 5.6K;
//      out_s [49][260] fp32 overlays the front only after proj reads die.
//  (2) P packed with v_cvt_pkrtz (1 instr, accuracy verified in R11).
// LDS = 71168 B -> still 2 blocks/CU (142336 < 160K).

typedef _Float16 half_t;
typedef _Float16 half8 __attribute__((ext_vector_type(8)));
typedef _Float16 half4 __attribute__((ext_vector_type(4)));
typedef float    f32x4 __attribute__((ext_vector_type(4)));

#define MFMA16(a, b, c) __builtin_amdgcn_mfma_f32_16x16x32_f16((a), (b), (c), 0, 0, 0)

__global__ __launch_bounds__(256) void convert_w(const float* __restrict__ qkv_w,
                                                 const float* __restrict__ proj_w,
                                                 half_t* __restrict__ w16) {
    int i = blockIdx.x * 256 + threadIdx.x;           // grid covers exactly 262144
    if (i < 768 * 256) w16[i] = (half_t)qkv_w[i];
    else               w16[i] = (half_t)proj_w[i - 768 * 256];
}

// pack two f32 -> one dword of 2 fp16 (RNE; used for Q/K/V)
static __device__ __forceinline__ unsigned pk2(float a, float b) {
    union { half_t h[2]; unsigned u; } t;
    t.h[0] = (half_t)a; t.h[1] = (half_t)b; return t.u;
}
// pack two f32 -> one dword of 2 fp16 (RTZ, single instr; used for P)
static __device__ __forceinline__ unsigned pk2z(float a, float b) {
    return __builtin_bit_cast(unsigned, __builtin_amdgcn_cvt_pkrtz(a, b));
}

// Build an A/B-frag (8 fp16): element C[8g+j][l15] of the C-layout tile pair
// (p0 = rows 0..15, p1 = rows 16..31), pairs packed along rows (K-dim).
static __device__ __forceinline__ half8 frag_pk(unsigned p0l, unsigned p0h,
                                                unsigned p1l, unsigned p1h,
                                                int srcA, int srcB, bool lo) {
    unsigned a0 = __shfl(p0l, srcA, 64), a1 = __shfl(p0h, srcA, 64);
    unsigned a2 = __shfl(p0l, srcB, 64), a3 = __shfl(p0h, srcB, 64);
    unsigned b0 = __shfl(p1l, srcA, 64), b1 = __shfl(p1h, srcA, 64);
    unsigned b2 = __shfl(p1l, srcB, 64), b3 = __shfl(p1h, srcB, 64);
    uint4 fr;
    fr.x = lo ? a0 : b0; fr.y = lo ? a1 : b1;
    fr.z = lo ? a2 : b2; fr.w = lo ? a3 : b3;
    return __builtin_bit_cast(half8, fr);
}

__global__ __launch_bounds__(512, 4) void winattn_mfma(
    const float* __restrict__ x,
    const float* __restrict__ qkv_b,
    const float* __restrict__ proj_b,
    const float* __restrict__ bias_table,
    const half_t* __restrict__ w16,
    float* __restrict__ out)
{
    constexpr int C = 256;
    __shared__ __align__(16) char smem[71168];
    char*  o_tile = smem + 32768;                     // [64][512B] swizzled fp16
    float* bias_s = (float*)(smem + 65536);           // [8][176] fp32 * log2e
    float* out_s  = (float*)smem;                     // [49][260] fp32 (late)

    const int tid  = threadIdx.x;
    const int wave = tid >> 6;
    const int lane = tid & 63;
    const int g    = lane >> 4;
    const int l15  = lane & 15;

    const int wid = blockIdx.x;
    const int b   = wid >> 6;
    const int wy  = (wid >> 3) & 7;
    const int wx  = wid & 7;
    const float* xbase = x   + (size_t)b * 3136 * C;
    float*       obase = out + (size_t)b * 3136 * C;

    const float LOG2E = 1.4426950408889634f;

    // bias_table is [169][8]; store transposed as [h][idx], pre-scaled by log2e
    for (int i = tid; i < 169 * 8; i += 512)
        bias_s[(i & 7) * 176 + (i >> 3)] = bias_table[i] * LOG2E;

    // ---- stage X fp32->fp16 [64][256], rows 49..63 zero, swizzle byte^=(row&15)<<4
    for (int i = tid; i < 64 * 32; i += 512) {
        int row = i >> 5, ch = i & 31;
        char* dst = smem + row * 512 + ((ch * 16) ^ ((row & 15) << 4));
        if (row < 49) {
            int ti = row / 7, tj = row % 7;
            const float* src = xbase + ((wy * 7 + ti) * 56 + (wx * 7 + tj)) * C + ch * 8;
            float4 f0 = ((const float4*)src)[0];
            float4 f1 = ((const float4*)src)[1];
            half8 v = { (half_t)f0.x, (half_t)f0.y, (half_t)f0.z, (half_t)f0.w,
                        (half_t)f1.x, (half_t)f1.y, (half_t)f1.z, (half_t)f1.w };
            *(half8*)dst = v;
        } else {
            half8 v = { (half_t)0, (half_t)0, (half_t)0, (half_t)0,
                        (half_t)0, (half_t)0, (half_t)0, (half_t)0 };
            *(half8*)dst = v;
        }
    }
    __syncthreads();

    const int h = wave;
    const int srcA = (g & 1) * 32 + l15;
    const int srcB = srcA + 16;
    const bool lo = (g < 2);
    const f32x4 fz = {0.f, 0.f, 0.f, 0.f};
    // scale * log2e folded together: S*log2e comes out of the MFMA via Q
    const float SCALE2 = 0.17677669529663687f * 1.4426950408889634f;

    // ================= pass 1: Q^T,K^T = W*X^T  (M=d 2 tiles, N=t 4 tiles)
    f32x4 qacc[2][4], kacc[2][4];
    #pragma unroll
    for (int mt = 0; mt < 2; ++mt)
        #pragma unroll
        for (int nt = 0; nt < 4; ++nt) { qacc[mt][nt] = fz; kacc[mt][nt] = fz; }

    #pragma unroll
    for (int s = 0; s < 8; ++s) {
        half8 xf[4];
        #pragma unroll
        for (int nt = 0; nt < 4; ++nt) {
            int row = nt * 16 + l15;
            xf[nt] = *(const half8*)(smem + row * 512 + ((s * 64 + g * 16) ^ ((row & 15) << 4)));
        }
        half8 wqf[2], wkf[2];
        #pragma unroll
        for (int mt = 0; mt < 2; ++mt) {
            int d = h * 32 + mt * 16 + l15;
            wqf[mt] = *(const half8*)(w16 + (size_t)d * 256 + s * 32 + g * 8);
            wkf[mt] = *(const half8*)(w16 + (size_t)(256 + d) * 256 + s * 32 + g * 8);
        }
        #pragma unroll
        for (int mt = 0; mt < 2; ++mt)
            #pragma unroll
            for (int nt = 0; nt < 4; ++nt) {
                qacc[mt][nt] = MFMA16(wqf[mt], xf[nt], qacc[mt][nt]);
                kacc[mt][nt] = MFMA16(wkf[mt], xf[nt], kacc[mt][nt]);
            }
    }

    // pack Q^T (bias, *scale*log2e) / K^T (bias) to fp16 dwords
    unsigned pkq[2][4][2], pkk[2][4][2];
    #pragma unroll
    for (int mt = 0; mt < 2; ++mt) {
        float bq[4], bk[4];
        #pragma unroll
        for (int r = 0; r < 4; ++r) {
            int d = h * 32 + mt * 16 + 4 * g + r;
            bq[r] = qkv_b[d];
            bk[r] = qkv_b[256 + d];
        }
        #pragma unroll
        for (int nt = 0; nt < 4; ++nt) {
            pkq[mt][nt][0] = pk2((qacc[mt][nt][0] + bq[0]) * SCALE2,
                                 (qacc[mt][nt][1] + bq[1]) * SCALE2);
            pkq[mt][nt][1] = pk2((qacc[mt][nt][2] + bq[2]) * SCALE2,
                                 (qacc[mt][nt][3] + bq[3]) * SCALE2);
            pkk[mt][nt][0] = pk2(kacc[mt][nt][0] + bk[0], kacc[mt][nt][1] + bk[1]);
            pkk[mt][nt][1] = pk2(kacc[mt][nt][2] + bk[2], kacc[mt][nt][3] + bk[3]);
        }
    }

    // ================= pass 2: S^T(*log2e) = K * Q^T  (M=k, N=q, K=32)
    half8 bqf[4];
    #pragma unroll
    for (int nt = 0; nt < 4; ++nt)
        bqf[nt] = frag_pk(pkq[0][nt][0], pkq[0][nt][1],
                          pkq[1][nt][0], pkq[1][nt][1], srcA, srcB, lo);
    f32x4 st[4][4];
    #pragma unroll
    for (int mt = 0; mt < 4; ++mt)
        #pragma unroll
        for (int nt = 0; nt < 4; ++nt) st[mt][nt] = fz;
    #pragma unroll
    for (int mt = 0; mt < 4; ++mt) {
        half8 ak = frag_pk(pkk[0][mt][0], pkk[0][mt][1],
                           pkk[1][mt][0], pkk[1][mt][1], srcA, srcB, lo);
        #pragma unroll
        for (int nt = 0; nt < 4; ++nt)
            st[mt][nt] = MFMA16(ak, bqf[nt], st[mt][nt]);
    }

    // ---- max-free softmax over k (base-2). masked k -> e=0. (R10 form --
    // per-element bias gather; R11's batched bb[16] spilled.)
    int qcode[4];
    #pragma unroll
    for (int nt = 0; nt < 4; ++nt) {
        int q = nt * 16 + l15; if (q > 48) q = 48;
        qcode[nt] = (q / 7) * 13 + (q % 7) + 84;
    }
    const float* bias_h = bias_s + h * 176;
    float sm0[4] = {0.f, 0.f, 0.f, 0.f};     // partials r=0,1
    float sm1[4] = {0.f, 0.f, 0.f, 0.f};     // partials r=2,3
    #pragma unroll
    for (int mt = 0; mt < 4; ++mt)
        #pragma unroll
        for (int r = 0; r < 4; ++r) {
            int k = mt * 16 + 4 * g + r;
            bool valid = (k < 49);
            int kc = valid ? ((k / 7) * 13 + (k % 7)) : 0;
            #pragma unroll
            for (int nt = 0; nt < 4; ++nt) {
                float e = valid
                    ? __builtin_amdgcn_exp2f(st[mt][nt][r] + bias_h[qcode[nt] - kc])
                    : 0.f;
                st[mt][nt][r] = e;
                if (r < 2) sm0[nt] += e; else sm1[nt] += e;
            }
        }
    float inv[4];
    #pragma unroll
    for (int nt = 0; nt < 4; ++nt) {
        float s2 = sm0[nt] + sm1[nt];
        float ssum = s2 + __shfl_xor(s2, 16, 64);
        ssum += __shfl_xor(ssum, 32, 64);
        inv[nt] = 1.0f / ssum;
    }
    // pack normalized P (RTZ single-instr pack; accuracy verified R11).
    // st dies here -> registers free for vacc below (do NOT move V GEMM
    // above this point: R8 did and spilled to scratch).
    unsigned pkp[4][4][2];
    #pragma unroll
    for (int mt = 0; mt < 4; ++mt)
        #pragma unroll
        for (int nt = 0; nt < 4; ++nt) {
            pkp[mt][nt][0] = pk2z(st[mt][nt][0] * inv[nt], st[mt][nt][1] * inv[nt]);
            pkp[mt][nt][1] = pk2z(st[mt][nt][2] * inv[nt], st[mt][nt][3] * inv[nt]);
        }

    // ================= pass 3: V = X * Wv^T  (M=t 4 tiles, N=d 2 tiles)
    f32x4 vacc[4][2];
    #pragma unroll
    for (int mt = 0; mt < 4; ++mt)
        #pragma unroll
        for (int nd = 0; nd < 2; ++nd) vacc[mt][nd] = fz;
    #pragma unroll
    for (int s = 0; s < 8; ++s) {
        half8 xf[4];
        #pragma unroll
        for (int mt = 0; mt < 4; ++mt) {
            int row = mt * 16 + l15;
            xf[mt] = *(const half8*)(smem + row * 512 + ((s * 64 + g * 16) ^ ((row & 15) << 4)));
        }
        half8 wvf[2];
        #pragma unroll
        for (int nd = 0; nd < 2; ++nd) {
            int d = 512 + h * 32 + nd * 16 + l15;
            wvf[nd] = *(const half8*)(w16 + (size_t)d * 256 + s * 32 + g * 8);
        }
        #pragma unroll
        for (int mt = 0; mt < 4; ++mt)
            #pragma unroll
            for (int nd = 0; nd < 2; ++nd)
                vacc[mt][nd] = MFMA16(xf[mt], wvf[nd], vacc[mt][nd]);
    }
    unsigned pkv[4][2][2];
    #pragma unroll
    for (int nd = 0; nd < 2; ++nd) {
        float bv = qkv_b[512 + h * 32 + nd * 16 + l15];
        #pragma unroll
        for (int mt = 0; mt < 4; ++mt) {
            pkv[mt][nd][0] = pk2(vacc[mt][nd][0] + bv, vacc[mt][nd][1] + bv);
            pkv[mt][nd][1] = pk2(vacc[mt][nd][2] + bv, vacc[mt][nd][3] + bv);
        }
    }

    // ================= pass 4: O^T = V^T * P^T  (M=d 2 tiles, N=q 4 tiles, K=64)
    f32x4 oacc[2][4];
    #pragma unroll
    for (int md = 0; md < 2; ++md)
        #pragma unroll
        for (int nq = 0; nq < 4; ++nq) oacc[md][nq] = fz;
    #pragma unroll
    for (int ks = 0; ks < 2; ++ks) {
        half8 avf[2];
        #pragma unroll
        for (int md = 0; md < 2; ++md)
            avf[md] = frag_pk(pkv[2 * ks][md][0], pkv[2 * ks][md][1],
                              pkv[2 * ks + 1][md][0], pkv[2 * ks + 1][md][1],
                              srcA, srcB, lo);
        #pragma unroll
        for (int nq = 0; nq < 4; ++nq) {
            half8 bpf = frag_pk(pkp[2 * ks][nq][0], pkp[2 * ks][nq][1],
                                pkp[2 * ks + 1][nq][0], pkp[2 * ks + 1][nq][1],
                                srcA, srcB, lo);
            #pragma unroll
            for (int md = 0; md < 2; ++md)
                oacc[md][nq] = MFMA16(avf[md], bpf, oacc[md][nq]);
        }
    }

    // ---- O write straight to its own region (no barrier needed first):
    // 8x ds_write_b64, conflict-free under the 4-bit swizzle
    #pragma unroll
    for (int md = 0; md < 2; ++md)
        #pragma unroll
        for (int nq = 0; nq < 4; ++nq) {
            int q = nq * 16 + l15;
            int dbase = h * 32 + md * 16 + 4 * g;          // 4 consecutive d
            half4 ov = { (half_t)oacc[md][nq][0], (half_t)oacc[md][nq][1],
                         (half_t)oacc[md][nq][2], (half_t)oacc[md][nq][3] };
            *(half4*)(o_tile + q * 512 + ((dbase * 2) ^ ((q & 15) << 4))) = ov;
        }
    __syncthreads();   // all heads' O visible before proj

    // ================= proj (operand-swapped): C = Wp * O^T
    // A = proj-weight rows (feats), B = O^T frags (tokens as cols) ->
    // C rows = feats: each thread holds 4 consecutive feats per token.
    const half_t* pw = w16 + 768 * 256;
    f32x4 pa[2][4];                                   // [feat tile][tok tile]
    #pragma unroll
    for (int mtf = 0; mtf < 2; ++mtf)
        #pragma unroll
        for (int nq = 0; nq < 4; ++nq) pa[mtf][nq] = fz;
    #pragma unroll
    for (int s = 0; s < 8; ++s) {
        half8 of[4], wf[2];
        #pragma unroll
        for (int nq = 0; nq < 4; ++nq) {
            int row = nq * 16 + l15;
            of[nq] = *(const half8*)(o_tile + row * 512 + ((s * 64 + g * 16) ^ ((row & 15) << 4)));
        }
        #pragma unroll
        for (int mtf = 0; mtf < 2; ++mtf) {
            int f = wave * 32 + mtf * 16 + l15;
            wf[mtf] = *(const half8*)(pw + (size_t)f * 256 + s * 32 + g * 8);
        }
        #pragma unroll
        for (int mtf = 0; mtf < 2; ++mtf)
            #pragma unroll
            for (int nq = 0; nq < 4; ++nq)
                pa[mtf][nq] = MFMA16(wf[mtf], of[nq], pa[mtf][nq]);
    }

    // proj reads done; out_s (fp32) may now overlay the X/O front region
    __syncthreads();

    // ---- stage proj output (+bias) into out_s [49][260] fp32: b128 writes
    #pragma unroll
    for (int mtf = 0; mtf < 2; ++mtf) {
        int fbase = wave * 32 + mtf * 16 + 4 * g;      // 4 consecutive feats
        float4 pbv = *(const float4*)&proj_b[fbase];
        #pragma unroll
        for (int nq = 0; nq < 4; ++nq) {
            int tok = nq * 16 + l15;
            if (tok < 49) {
                float4 v = { pa[mtf][nq][0] + pbv.x, pa[mtf][nq][1] + pbv.y,
                             pa[mtf][nq][2] + pbv.z, pa[mtf][nq][3] + pbv.w };
                *(float4*)&out_s[tok * 260 + fbase] = v;
            }
        }
    }
    __syncthreads();

    // ---- write out: one full 1KB token row per wave iteration (fully
    // coalesced, every 128B line visited exactly once)
    for (int i = tid; i < 49 * 64; i += 512) {
        int t = i >> 6, c4 = i & 63;
        float4 v = *(const float4*)&out_s[t * 260 + c4 * 4];
        int ti = t / 7, tj = t % 7;
        *(float4*)&obase[((wy * 7 + ti) * 56 + (wx * 7 + tj)) * C + c4 * 4] = v;
    }
}

extern "C" void kernel_launch(void* const* d_in, const int* in_sizes, int n_in,
                              void* d_out, int out_size, void* d_ws, size_t ws_size,
                              hipStream_t stream) {
    const float* x          = (const float*)d_in[0];
    const float* qkv_w      = (const float*)d_in[3];
    const float* qkv_b      = (const float*)d_in[4];
    const float* proj_w     = (const float*)d_in[5];
    const float* proj_b     = (const float*)d_in[6];
    const float* bias_table = (const float*)d_in[7];
    float* out = (float*)d_out;
    half_t* w16 = (half_t*)d_ws;   // 1024*256 halfs = 524288 B

    hipLaunchKernelGGL(convert_w, dim3(1024), dim3(256), 0, stream,
                       qkv_w, proj_w, w16);
    hipLaunchKernelGGL(winattn_mfma, dim3(2048), dim3(512), 0, stream,
                       x, qkv_b, proj_b, bias_table, w16, out);
}

// Round 13
// 124.938 us; speedup vs baseline: 1.4319x; 1.2851x over previous
//
#include <hip/hip_runtime.h>

// Window attention, register-resident MFMA version (R13).
// One WG (512 thr = 8 waves) per 7x7 window; wave = head.
// R13 vs R12: weights repacked in convert_w into MFMA-fragment order:
// chunk[(which,head,tile,s)] = 64 lanes x 16B, so every weight load in
// pass1/pass3/proj is ONE fully-coalesced b128 at base+chunk*1024+lane*16
// (was 16 rows at 512B stride = 16 half-used L2 lines + mul/shift addr chain).
// Register-neutral; kernel structure identical to R12.
// LDS = 71168 B -> 2 blocks/CU.

typedef _Float16 half_t;
typedef _Float16 half8 __attribute__((ext_vector_type(8)));
typedef _Float16 half4 __attribute__((ext_vector_type(4)));
typedef float    f32x4 __attribute__((ext_vector_type(4)));

#define MFMA16(a, b, c) __builtin_amdgcn_mfma_f32_16x16x32_f16((a), (b), (c), 0, 0, 0)

// Repack fp32 weights -> fp16 fragment chunks.
// chunk = ((which*8 + hh)*2 + mt)*8 + s   (which: 0=Q 1=K 2=V 3=proj)
// element: packed[chunk*512 + (g*16+l15)*8 + j] = W[row][col],
//   row = which<3 ? which*256 + hh*32 + mt*16 + l15 : hh*32 + mt*16 + l15
//   col = s*32 + g*8 + j
__global__ __launch_bounds__(256) void convert_w(const float* __restrict__ qkv_w,
                                                 const float* __restrict__ proj_w,
                                                 half_t* __restrict__ w16) {
    int i = blockIdx.x * 256 + threadIdx.x;           // 262144 total
    int j     = i & 7;
    int lane  = (i >> 3) & 63;
    int chunk = i >> 9;
    int g   = lane >> 4, l15 = lane & 15;
    int s   = chunk & 7;
    int mt  = (chunk >> 3) & 1;
    int hh  = (chunk >> 4) & 7;
    int which = chunk >> 7;
    int col = s * 32 + g * 8 + j;
    float v;
    if (which < 3) {
        int d = which * 256 + hh * 32 + mt * 16 + l15;
        v = qkv_w[d * 256 + col];
    } else {
        int f = hh * 32 + mt * 16 + l15;
        v = proj_w[f * 256 + col];
    }
    w16[i] = (half_t)v;
}

// pack two f32 -> one dword of 2 fp16 (RNE; used for Q/K/V)
static __device__ __forceinline__ unsigned pk2(float a, float b) {
    union { half_t h[2]; unsigned u; } t;
    t.h[0] = (half_t)a; t.h[1] = (half_t)b; return t.u;
}
// pack two f32 -> one dword of 2 fp16 (RTZ, single instr; used for P)
static __device__ __forceinline__ unsigned pk2z(float a, float b) {
    return __builtin_bit_cast(unsigned, __builtin_amdgcn_cvt_pkrtz(a, b));
}

// Build an A/B-frag (8 fp16): element C[8g+j][l15] of the C-layout tile pair
// (p0 = rows 0..15, p1 = rows 16..31), pairs packed along rows (K-dim).
static __device__ __forceinline__ half8 frag_pk(unsigned p0l, unsigned p0h,
                                                unsigned p1l, unsigned p1h,
                                                int srcA, int srcB, bool lo) {
    unsigned a0 = __shfl(p0l, srcA, 64), a1 = __shfl(p0h, srcA, 64);
    unsigned a2 = __shfl(p0l, srcB, 64), a3 = __shfl(p0h, srcB, 64);
    unsigned b0 = __shfl(p1l, srcA, 64), b1 = __shfl(p1h, srcA, 64);
    unsigned b2 = __shfl(p1l, srcB, 64), b3 = __shfl(p1h, srcB, 64);
    uint4 fr;
    fr.x = lo ? a0 : b0; fr.y = lo ? a1 : b1;
    fr.z = lo ? a2 : b2; fr.w = lo ? a3 : b3;
    return __builtin_bit_cast(half8, fr);
}

__global__ __launch_bounds__(512, 4) void winattn_mfma(
    const float* __restrict__ x,
    const float* __restrict__ qkv_b,
    const float* __restrict__ proj_b,
    const float* __restrict__ bias_table,
    const half_t* __restrict__ w16,
    float* __restrict__ out)
{
    constexpr int C = 256;
    __shared__ __align__(16) char smem[71168];
    char*  o_tile = smem + 32768;                     // [64][512B] swizzled fp16
    float* bias_s = (float*)(smem + 65536);           // [8][176] fp32 * log2e
    float* out_s  = (float*)smem;                     // [49][260] fp32 (late)

    const int tid  = threadIdx.x;
    const int wave = tid >> 6;
    const int lane = tid & 63;
    const int g    = lane >> 4;
    const int l15  = lane & 15;

    const int wid = blockIdx.x;
    const int b   = wid >> 6;
    const int wy  = (wid >> 3) & 7;
    const int wx  = wid & 7;
    const float* xbase = x   + (size_t)b * 3136 * C;
    float*       obase = out + (size_t)b * 3136 * C;

    const float LOG2E = 1.4426950408889634f;

    // bias_table is [169][8]; store transposed as [h][idx], pre-scaled by log2e
    for (int i = tid; i < 169 * 8; i += 512)
        bias_s[(i & 7) * 176 + (i >> 3)] = bias_table[i] * LOG2E;

    // ---- stage X fp32->fp16 [64][256], rows 49..63 zero, swizzle byte^=(row&15)<<4
    for (int i = tid; i < 64 * 32; i += 512) {
        int row = i >> 5, ch = i & 31;
        char* dst = smem + row * 512 + ((ch * 16) ^ ((row & 15) << 4));
        if (row < 49) {
            int ti = row / 7, tj = row % 7;
            const float* src = xbase + ((wy * 7 + ti) * 56 + (wx * 7 + tj)) * C + ch * 8;
            float4 f0 = ((const float4*)src)[0];
            float4 f1 = ((const float4*)src)[1];
            half8 v = { (half_t)f0.x, (half_t)f0.y, (half_t)f0.z, (half_t)f0.w,
                        (half_t)f1.x, (half_t)f1.y, (half_t)f1.z, (half_t)f1.w };
            *(half8*)dst = v;
        } else {
            half8 v = { (half_t)0, (half_t)0, (half_t)0, (half_t)0,
                        (half_t)0, (half_t)0, (half_t)0, (half_t)0 };
            *(half8*)dst = v;
        }
    }
    __syncthreads();

    const int h = wave;
    const int srcA = (g & 1) * 32 + l15;
    const int srcB = srcA + 16;
    const bool lo = (g < 2);
    const f32x4 fz = {0.f, 0.f, 0.f, 0.f};
    // scale * log2e folded together: S*log2e comes out of the MFMA via Q
    const float SCALE2 = 0.17677669529663687f * 1.4426950408889634f;

    // per-wave packed-weight bases (chunk stride 512 halfs = 1KB)
    const half_t* wq_b = w16 + (size_t)(((0 * 8 + h) * 2) * 8) * 512 + lane * 8;
    const half_t* wk_b = w16 + (size_t)(((1 * 8 + h) * 2) * 8) * 512 + lane * 8;
    const half_t* wv_b = w16 + (size_t)(((2 * 8 + h) * 2) * 8) * 512 + lane * 8;
    const half_t* wp_b = w16 + (size_t)(((3 * 8 + h) * 2) * 8) * 512 + lane * 8;

    // ================= pass 1: Q^T,K^T = W*X^T  (M=d 2 tiles, N=t 4 tiles)
    f32x4 qacc[2][4], kacc[2][4];
    #pragma unroll
    for (int mt = 0; mt < 2; ++mt)
        #pragma unroll
        for (int nt = 0; nt < 4; ++nt) { qacc[mt][nt] = fz; kacc[mt][nt] = fz; }

    #pragma unroll
    for (int s = 0; s < 8; ++s) {
        half8 xf[4];
        #pragma unroll
        for (int nt = 0; nt < 4; ++nt) {
            int row = nt * 16 + l15;
            xf[nt] = *(const half8*)(smem + row * 512 + ((s * 64 + g * 16) ^ ((row & 15) << 4)));
        }
        half8 wqf[2], wkf[2];
        #pragma unroll
        for (int mt = 0; mt < 2; ++mt) {
            wqf[mt] = *(const half8*)(wq_b + (mt * 8 + s) * 512);
            wkf[mt] = *(const half8*)(wk_b + (mt * 8 + s) * 512);
        }
        #pragma unroll
        for (int mt = 0; mt < 2; ++mt)
            #pragma unroll
            for (int nt = 0; nt < 4; ++nt) {
                qacc[mt][nt] = MFMA16(wqf[mt], xf[nt], qacc[mt][nt]);
                kacc[mt][nt] = MFMA16(wkf[mt], xf[nt], kacc[mt][nt]);
            }
    }

    // pack Q^T (bias, *scale*log2e) / K^T (bias) to fp16 dwords
    unsigned pkq[2][4][2], pkk[2][4][2];
    #pragma unroll
    for (int mt = 0; mt < 2; ++mt) {
        float bq[4], bk[4];
        #pragma unroll
        for (int r = 0; r < 4; ++r) {
            int d = h * 32 + mt * 16 + 4 * g + r;
            bq[r] = qkv_b[d];
            bk[r] = qkv_b[256 + d];
        }
        #pragma unroll
        for (int nt = 0; nt < 4; ++nt) {
            pkq[mt][nt][0] = pk2((qacc[mt][nt][0] + bq[0]) * SCALE2,
                                 (qacc[mt][nt][1] + bq[1]) * SCALE2);
            pkq[mt][nt][1] = pk2((qacc[mt][nt][2] + bq[2]) * SCALE2,
                                 (qacc[mt][nt][3] + bq[3]) * SCALE2);
            pkk[mt][nt][0] = pk2(kacc[mt][nt][0] + bk[0], kacc[mt][nt][1] + bk[1]);
            pkk[mt][nt][1] = pk2(kacc[mt][nt][2] + bk[2], kacc[mt][nt][3] + bk[3]);
        }
    }

    // ================= pass 2: S^T(*log2e) = K * Q^T  (M=k, N=q, K=32)
    half8 bqf[4];
    #pragma unroll
    for (int nt = 0; nt < 4; ++nt)
        bqf[nt] = frag_pk(pkq[0][nt][0], pkq[0][nt][1],
                          pkq[1][nt][0], pkq[1][nt][1], srcA, srcB, lo);
    f32x4 st[4][4];
    #pragma unroll
    for (int mt = 0; mt < 4; ++mt)
        #pragma unroll
        for (int nt = 0; nt < 4; ++nt) st[mt][nt] = fz;
    #pragma unroll
    for (int mt = 0; mt < 4; ++mt) {
        half8 ak = frag_pk(pkk[0][mt][0], pkk[0][mt][1],
                           pkk[1][mt][0], pkk[1][mt][1], srcA, srcB, lo);
        #pragma unroll
        for (int nt = 0; nt < 4; ++nt)
            st[mt][nt] = MFMA16(ak, bqf[nt], st[mt][nt]);
    }

    // ---- max-free softmax over k (base-2). masked k -> e=0.
    int qcode[4];
    #pragma unroll
    for (int nt = 0; nt < 4; ++nt) {
        int q = nt * 16 + l15; if (q > 48) q = 48;
        qcode[nt] = (q / 7) * 13 + (q % 7) + 84;
    }
    const float* bias_h = bias_s + h * 176;
    float sm0[4] = {0.f, 0.f, 0.f, 0.f};     // partials r=0,1
    float sm1[4] = {0.f, 0.f, 0.f, 0.f};     // partials r=2,3
    #pragma unroll
    for (int mt = 0; mt < 4; ++mt)
        #pragma unroll
        for (int r = 0; r < 4; ++r) {
            int k = mt * 16 + 4 * g + r;
            bool valid = (k < 49);
            int kc = valid ? ((k / 7) * 13 + (k % 7)) : 0;
            #pragma unroll
            for (int nt = 0; nt < 4; ++nt) {
                float e = valid
                    ? __builtin_amdgcn_exp2f(st[mt][nt][r] + bias_h[qcode[nt] - kc])
                    : 0.f;
                st[mt][nt][r] = e;
                if (r < 2) sm0[nt] += e; else sm1[nt] += e;
            }
        }
    float inv[4];
    #pragma unroll
    for (int nt = 0; nt < 4; ++nt) {
        float s2 = sm0[nt] + sm1[nt];
        float ssum = s2 + __shfl_xor(s2, 16, 64);
        ssum += __shfl_xor(ssum, 32, 64);
        inv[nt] = 1.0f / ssum;
    }
    // pack normalized P (RTZ single-instr pack). st dies here -> registers
    // free for vacc below (do NOT move V GEMM above this point: R8 spilled).
    unsigned pkp[4][4][2];
    #pragma unroll
    for (int mt = 0; mt < 4; ++mt)
        #pragma unroll
        for (int nt = 0; nt < 4; ++nt) {
            pkp[mt][nt][0] = pk2z(st[mt][nt][0] * inv[nt], st[mt][nt][1] * inv[nt]);
            pkp[mt][nt][1] = pk2z(st[mt][nt][2] * inv[nt], st[mt][nt][3] * inv[nt]);
        }

    // ================= pass 3: V = X * Wv^T  (M=t 4 tiles, N=d 2 tiles)
    f32x4 vacc[4][2];
    #pragma unroll
    for (int mt = 0; mt < 4; ++mt)
        #pragma unroll
        for (int nd = 0; nd < 2; ++nd) vacc[mt][nd] = fz;
    #pragma unroll
    for (int s = 0; s < 8; ++s) {
        half8 xf[4];
        #pragma unroll
        for (int mt = 0; mt < 4; ++mt) {
            int row = mt * 16 + l15;
            xf[mt] = *(const half8*)(smem + row * 512 + ((s * 64 + g * 16) ^ ((row & 15) << 4)));
        }
        half8 wvf[2];
        #pragma unroll
        for (int nd = 0; nd < 2; ++nd)
            wvf[nd] = *(const half8*)(wv_b + (nd * 8 + s) * 512);
        #pragma unroll
        for (int mt = 0; mt < 4; ++mt)
            #pragma unroll
            for (int nd = 0; nd < 2; ++nd)
                vacc[mt][nd] = MFMA16(xf[mt], wvf[nd], vacc[mt][nd]);
    }
    unsigned pkv[4][2][2];
    #pragma unroll
    for (int nd = 0; nd < 2; ++nd) {
        float bv = qkv_b[512 + h * 32 + nd * 16 + l15];
        #pragma unroll
        for (int mt = 0; mt < 4; ++mt) {
            pkv[mt][nd][0] = pk2(vacc[mt][nd][0] + bv, vacc[mt][nd][1] + bv);
            pkv[mt][nd][1] = pk2(vacc[mt][nd][2] + bv, vacc[mt][nd][3] + bv);
        }
    }

    // ================= pass 4: O^T = V^T * P^T  (M=d 2 tiles, N=q 4 tiles, K=64)
    f32x4 oacc[2][4];
    #pragma unroll
    for (int md = 0; md < 2; ++md)
        #pragma unroll
        for (int nq = 0; nq < 4; ++nq) oacc[md][nq] = fz;
    #pragma unroll
    for (int ks = 0; ks < 2; ++ks) {
        half8 avf[2];
        #pragma unroll
        for (int md = 0; md < 2; ++md)
            avf[md] = frag_pk(pkv[2 * ks][md][0], pkv[2 * ks][md][1],
                              pkv[2 * ks + 1][md][0], pkv[2 * ks + 1][md][1],
                              srcA, srcB, lo);
        #pragma unroll
        for (int nq = 0; nq < 4; ++nq) {
            half8 bpf = frag_pk(pkp[2 * ks][nq][0], pkp[2 * ks][nq][1],
                                pkp[2 * ks + 1][nq][0], pkp[2 * ks + 1][nq][1],
                                srcA, srcB, lo);
            #pragma unroll
            for (int md = 0; md < 2; ++md)
                oacc[md][nq] = MFMA16(avf[md], bpf, oacc[md][nq]);
        }
    }

    // ---- O write straight to its own region (no barrier needed first):
    // 8x ds_write_b64, conflict-free under the 4-bit swizzle
    #pragma unroll
    for (int md = 0; md < 2; ++md)
        #pragma unroll
        for (int nq = 0; nq < 4; ++nq) {
            int q = nq * 16 + l15;
            int dbase = h * 32 + md * 16 + 4 * g;          // 4 consecutive d
            half4 ov = { (half_t)oacc[md][nq][0], (half_t)oacc[md][nq][1],
                         (half_t)oacc[md][nq][2], (half_t)oacc[md][nq][3] };
            *(half4*)(o_tile + q * 512 + ((dbase * 2) ^ ((q & 15) << 4))) = ov;
        }
    __syncthreads();   // all heads' O visible before proj

    // ================= proj (operand-swapped): C = Wp * O^T
    f32x4 pa[2][4];                                   // [feat tile][tok tile]
    #pragma unroll
    for (int mtf = 0; mtf < 2; ++mtf)
        #pragma unroll
        for (int nq = 0; nq < 4; ++nq) pa[mtf][nq] = fz;
    #pragma unroll
    for (int s = 0; s < 8; ++s) {
        half8 of[4], wf[2];
        #pragma unroll
        for (int nq = 0; nq < 4; ++nq) {
            int row = nq * 16 + l15;
            of[nq] = *(const half8*)(o_tile + row * 512 + ((s * 64 + g * 16) ^ ((row & 15) << 4)));
        }
        #pragma unroll
        for (int mtf = 0; mtf < 2; ++mtf)
            wf[mtf] = *(const half8*)(wp_b + (mtf * 8 + s) * 512);
        #pragma unroll
        for (int mtf = 0; mtf < 2; ++mtf)
            #pragma unroll
            for (int nq = 0; nq < 4; ++nq)
                pa[mtf][nq] = MFMA16(wf[mtf], of[nq], pa[mtf][nq]);
    }

    // proj reads done; out_s (fp32) may now overlay the X/O front region
    __syncthreads();

    // ---- stage proj output (+bias) into out_s [49][260] fp32: b128 writes
    #pragma unroll
    for (int mtf = 0; mtf < 2; ++mtf) {
        int fbase = wave * 32 + mtf * 16 + 4 * g;      // 4 consecutive feats
        float4 pbv = *(const float4*)&proj_b[fbase];
        #pragma unroll
        for (int nq = 0; nq < 4; ++nq) {
            int tok = nq * 16 + l15;
            if (tok < 49) {
                float4 v = { pa[mtf][nq][0] + pbv.x, pa[mtf][nq][1] + pbv.y,
                             pa[mtf][nq][2] + pbv.z, pa[mtf][nq][3] + pbv.w };
                *(float4*)&out_s[tok * 260 + fbase] = v;
            }
        }
    }
    __syncthreads();

    // ---- write out: one full 1KB token row per wave iteration (fully
    // coalesced, every 128B line visited exactly once)
    for (int i = tid; i < 49 * 64; i += 512) {
        int t = i >> 6, c4 = i & 63;
        float4 v = *(const float4*)&out_s[t * 260 + c4 * 4];
        int ti = t / 7, tj = t % 7;
        *(float4*)&obase[((wy * 7 + ti) * 56 + (wx * 7 + tj)) * C + c4 * 4] = v;
    }
}

extern "C" void kernel_launch(void* const* d_in, const int* in_sizes, int n_in,
                              void* d_out, int out_size, void* d_ws, size_t ws_size,
                              hipStream_t stream) {
    const float* x          = (const float*)d_in[0];
    const float* qkv_w      = (const float*)d_in[3];
    const float* qkv_b      = (const float*)d_in[4];
    const float* proj_w     = (const float*)d_in[5];
    const float* proj_b     = (const float*)d_in[6];
    const float* bias_table = (const float*)d_in[7];
    float* out = (float*)d_out;
    half_t* w16 = (half_t*)d_ws;   // 512 chunks x 1KB = 524288 B

    hipLaunchKernelGGL(convert_w, dim3(1024), dim3(256), 0, stream,
                       qkv_w, proj_w, w16);
    hipLaunchKernelGGL(winattn_mfma, dim3(2048), dim3(512), 0, stream,
                       x, qkv_b, proj_b, bias_table, w16, out);
}